// Round 1
// baseline (3709.690 us; speedup 1.0000x reference)
//
#include <hip/hip_runtime.h>

#define B_ 64
#define T_ 4096
#define D_ 128
#define H_ 256

// Barrier that waits only on LDS ops (lgkmcnt), NOT on in-flight global
// loads/stores (vmcnt). __syncthreads() would drain vmcnt(0) every step,
// serializing the xp prefetch (HBM ~900 cyc) and h store retire into the
// critical path. Our per-step cross-thread hazards are LDS-only.
//
// Hardened form: the s_barrier itself is the convergent builtin (the raw
// asm "s_barrier" is not marked convergent to LLVM and may in principle be
// duplicated across restructured control flow -> mismatched barrier counts
// -> hang). The builtin is IntrNoMem, so it does NOT order memory by
// itself: the leading asm (memory clobber) drains lgkmcnt and pins all
// prior LDS writes before the barrier; the trailing empty asm (memory
// clobber) stops later LDS reads from hoisting between waitcnt and barrier.
__device__ __forceinline__ void barrier_lgkm() {
    asm volatile("s_waitcnt lgkmcnt(0)" ::: "memory");
    __builtin_amdgcn_s_barrier();
    asm volatile("" ::: "memory");
}

// ---------------------------------------------------------------------------
// Kernel A: xp = x @ Wx + bx, written into `out`.
// grid = (B*T)/64 blocks, 1024 threads (16 waves -> 4/SIMD latency hiding).
// Thread (j = tid&255, q = tid>>8) computes rows [16q,16q+16) x column j.
// x tile (64x128 fp32 = 32 KB) in LDS; Wx (131 KB) stays L2-hot.
// ---------------------------------------------------------------------------
__global__ __launch_bounds__(1024) void xp_kernel(const float* __restrict__ x,
                                                  const float* __restrict__ Wx,
                                                  const float* __restrict__ bx,
                                                  float* __restrict__ out) {
    __shared__ float xs[64 * D_];
    const int tid = threadIdx.x;
    const int j = tid & 255;
    const int q = tid >> 8;                    // 0..3 -> rows 16q..16q+15
    const long row0 = (long)blockIdx.x * 64;

    // contiguous 8192-float tile load, float4-vectorized (2 per thread)
    const float4* xg = (const float4*)(x + row0 * D_);
    float4* xs4 = (float4*)xs;
    for (int i = tid; i < (64 * D_) / 4; i += 1024) xs4[i] = xg[i];
    __syncthreads();

    float acc[16];
#pragma unroll
    for (int r = 0; r < 16; ++r) acc[r] = 0.f;

    for (int k0 = 0; k0 < D_; k0 += 4) {
        const float w0 = Wx[(k0 + 0) * H_ + j];
        const float w1 = Wx[(k0 + 1) * H_ + j];
        const float w2 = Wx[(k0 + 2) * H_ + j];
        const float w3 = Wx[(k0 + 3) * H_ + j];
#pragma unroll
        for (int r = 0; r < 16; ++r) {
            const float4 xv = *(const float4*)(&xs[(q * 16 + r) * D_ + k0]);  // broadcast
            acc[r] += xv.x * w0 + xv.y * w1 + xv.z * w2 + xv.w * w3;
        }
    }

    const float bj = bx[j];
#pragma unroll
    for (int r = 0; r < 16; ++r) {
        out[(row0 + q * 16 + r) * H_ + j] = acc[r] + bj;   // coalesced across j
    }
}

// ---------------------------------------------------------------------------
// Kernel B: per-batch recurrence h_t = tanh(xp_t + h_{t-1} @ Wh + bh).
// grid = 64 blocks, 1024 threads. Thread (j, q) holds Wh[64q..64q+63][j]
// in registers. Per step: broadcast ds_read of h slice -> 64 FMAs ->
// partial via LDS (q!=0 only; q==0 keeps its own in reg) -> lgkm barrier ->
// q==0 reduces + fast tanh + store -> lgkm barrier. Global xp prefetch and
// h stores stay in flight across barriers (no vmcnt drain).
// ---------------------------------------------------------------------------
__global__ __launch_bounds__(1024) void rnn_kernel(const float* __restrict__ Wh,
                                                   const float* __restrict__ bh,
                                                   float* __restrict__ out) {
    const int b = blockIdx.x;
    const int tid = threadIdx.x;
    const int j = tid & 255;
    const int q = tid >> 8;                    // 0..3

    __shared__ float hs[H_];
    __shared__ float partial[3 * H_];          // written by q=1..3

    float wreg[64];
#pragma unroll
    for (int ii = 0; ii < 64; ++ii) wreg[ii] = Wh[(q * 64 + ii) * H_ + j];
    const float bhj = bh[j];

    if (tid < H_) hs[tid] = 0.f;
    __syncthreads();                           // once; vmcnt drain here is fine

    float* obase = out + (long)b * T_ * H_;
    float xp0 = 0.f, xp1 = 0.f;
    if (q == 0) {
        xp0 = obase[j];                        // xp[b][0][j]
        xp1 = obase[H_ + j];                   // xp[b][1][j]
    }

#pragma unroll 2
    for (int t = 0; t < T_; ++t) {
        // prefetch xp for t+2; vmcnt wait lands ~1 full step later
        float xp2 = 0.f;
        if (q == 0 && t + 2 < T_) xp2 = obase[(long)(t + 2) * H_ + j];

        float a0 = 0.f, a1 = 0.f, a2 = 0.f, a3 = 0.f;
#pragma unroll
        for (int ii = 0; ii < 64; ii += 4) {
            const float4 hv = *(const float4*)(&hs[q * 64 + ii]);  // broadcast
            a0 += hv.x * wreg[ii + 0];
            a1 += hv.y * wreg[ii + 1];
            a2 += hv.z * wreg[ii + 2];
            a3 += hv.w * wreg[ii + 3];
        }
        const float p = (a0 + a1) + (a2 + a3);
        if (q != 0) partial[(q - 1) * H_ + j] = p;
        barrier_lgkm();

        if (q == 0) {
            float s = p + partial[j] + partial[H_ + j] + partial[2 * H_ + j]
                      + xp0 + bhj;
            // branchless tanh: clamp, e = exp(2s), (e-1)/(e+1)
            s = fminf(15.f, fmaxf(-15.f, s));
            const float e = __expf(2.f * s);
            const float hn = __fdividef(e - 1.f, e + 1.f);
            hs[j] = hn;
            obase[(long)t * H_ + j] = hn;      // fire-and-forget store
            xp0 = xp1;
            xp1 = xp2;
        }
        barrier_lgkm();
    }
}

extern "C" void kernel_launch(void* const* d_in, const int* in_sizes, int n_in,
                              void* d_out, int out_size, void* d_ws, size_t ws_size,
                              hipStream_t stream) {
    const float* x  = (const float*)d_in[0];
    const float* Wx = (const float*)d_in[1];
    const float* bx = (const float*)d_in[2];
    const float* Wh = (const float*)d_in[3];
    const float* bh = (const float*)d_in[4];
    float* out = (float*)d_out;

    xp_kernel<<<(B_ * T_) / 64, 1024, 0, stream>>>(x, Wx, bx, out);
    rnn_kernel<<<B_, 1024, 0, stream>>>(Wh, bh, out);
}

// Round 5
// 3686.904 us; speedup vs baseline: 1.0062x; 1.0062x over previous
//
#include <hip/hip_runtime.h>

#define B_ 64
#define T_ 4096
#define D_ 128
#define H_ 256

// Barrier that waits only on LDS ops (lgkmcnt), NOT on in-flight global
// loads/stores (vmcnt). __syncthreads() would drain vmcnt(0) every step,
// serializing the xp prefetch (HBM ~900 cyc) and h store retire into the
// critical path. Our per-step cross-thread hazards are LDS-only.
__device__ __forceinline__ void barrier_lgkm() {
    asm volatile("s_waitcnt lgkmcnt(0)" ::: "memory");
    __builtin_amdgcn_s_barrier();
    asm volatile("" ::: "memory");
}

// ---------------------------------------------------------------------------
// Kernel A: xp = x @ Wx + bx, written into `out`. (unchanged this round)
// ---------------------------------------------------------------------------
__global__ __launch_bounds__(1024) void xp_kernel(const float* __restrict__ x,
                                                  const float* __restrict__ Wx,
                                                  const float* __restrict__ bx,
                                                  float* __restrict__ out) {
    __shared__ float xs[64 * D_];
    const int tid = threadIdx.x;
    const int j = tid & 255;
    const int q = tid >> 8;                    // 0..3 -> rows 16q..16q+15
    const long row0 = (long)blockIdx.x * 64;

    const float4* xg = (const float4*)(x + row0 * D_);
    float4* xs4 = (float4*)xs;
    for (int i = tid; i < (64 * D_) / 4; i += 1024) xs4[i] = xg[i];
    __syncthreads();

    float acc[16];
#pragma unroll
    for (int r = 0; r < 16; ++r) acc[r] = 0.f;

    for (int k0 = 0; k0 < D_; k0 += 4) {
        const float w0 = Wx[(k0 + 0) * H_ + j];
        const float w1 = Wx[(k0 + 1) * H_ + j];
        const float w2 = Wx[(k0 + 2) * H_ + j];
        const float w3 = Wx[(k0 + 3) * H_ + j];
#pragma unroll
        for (int r = 0; r < 16; ++r) {
            const float4 xv = *(const float4*)(&xs[(q * 16 + r) * D_ + k0]);  // broadcast
            acc[r] += xv.x * w0 + xv.y * w1 + xv.z * w2 + xv.w * w3;
        }
    }

    const float bj = bx[j];
#pragma unroll
    for (int r = 0; r < 16; ++r) {
        out[(row0 + q * 16 + r) * H_ + j] = acc[r] + bj;   // coalesced across j
    }
}

// ---------------------------------------------------------------------------
// Kernel B: per-batch recurrence h_t = tanh(xp_t + h_{t-1} @ Wh + bh).
// grid = 64 blocks, 1024 threads (16 waves).
//
// Register-blocked remap: wave s (=tid>>6) owns k-slice [16s,16s+16);
// lane l computes FOUR outputs j=4l..4l+3. Per step each wave issues only
// 4 broadcast ds_read_b128 of its h slice (64/CU/step, was 256) -> LDS
// return-bus traffic drops 4x, below the 512-cyc VALU-issue floor.
// Each thread holds Wh[16s..16s+15][4l..4l+3] = 16 float4 in registers.
// Reduction: every wave writes its 4 partials as one conflict-free b128 to
// partial[s][4l..4l+3]; after an lgkm barrier, waves 0..3 each reduce 64
// outputs (1/thread, jr=s*64+lane): 16 stride-1 b32 reads (2-way alias =
// free), tree-add, + xp + bias, fast tanh, hs write + coalesced store.
// Global xp prefetch (t+2) and h stores stay in flight across barriers.
// ---------------------------------------------------------------------------
__global__ __launch_bounds__(1024) void rnn_kernel(const float* __restrict__ Wh,
                                                   const float* __restrict__ bh,
                                                   float* __restrict__ out) {
    const int b = blockIdx.x;
    const int tid = threadIdx.x;
    const int lane = tid & 63;
    const int s = tid >> 6;                    // wave id 0..15 = k-slice
    const int j0 = lane << 2;                  // phase-1 outputs j0..j0+3
    const int jr = ((s & 3) << 6) + lane;      // phase-2 output (waves 0..3)

    __shared__ float hs[H_];
    __shared__ float partial[16][H_];

    // wreg[kk] = Wh[16s+kk][j0..j0+3]  (coalesced b128 loads, 64 VGPRs)
    float4 wreg[16];
#pragma unroll
    for (int kk = 0; kk < 16; ++kk)
        wreg[kk] = *(const float4*)(&Wh[(s * 16 + kk) * H_ + j0]);

    const float bhj = bh[jr];

    if (tid < H_) hs[tid] = 0.f;
    __syncthreads();                           // once; vmcnt drain here is fine

    float* obase = out + (long)b * T_ * H_;
    float xp0 = 0.f, xp1 = 0.f;
    if (s < 4) {
        xp0 = obase[jr];                       // xp[b][0][jr]
        xp1 = obase[H_ + jr];                  // xp[b][1][jr]
    }

#pragma unroll 2
    for (int t = 0; t < T_; ++t) {
        // prefetch xp for t+2; vmcnt wait lands ~1 full step later
        float xp2 = 0.f;
        if (s < 4 && t + 2 < T_) xp2 = obase[(long)(t + 2) * H_ + jr];

        // phase 1: 4 broadcast b128 reads + 64 FMAs into 4 accumulators
        float4 acc;
        acc.x = 0.f; acc.y = 0.f; acc.z = 0.f; acc.w = 0.f;
#define FMA4(HE, W) { const float he_ = (HE); const float4 w_ = (W); \
        acc.x += he_ * w_.x; acc.y += he_ * w_.y;                     \
        acc.z += he_ * w_.z; acc.w += he_ * w_.w; }
#pragma unroll
        for (int c = 0; c < 4; ++c) {
            const float4 hv = *(const float4*)(&hs[s * 16 + c * 4]);  // broadcast
            FMA4(hv.x, wreg[c * 4 + 0])
            FMA4(hv.y, wreg[c * 4 + 1])
            FMA4(hv.z, wreg[c * 4 + 2])
            FMA4(hv.w, wreg[c * 4 + 3])
        }
#undef FMA4
        *(float4*)(&partial[s][j0]) = acc;     // conflict-free b128 write
        barrier_lgkm();

        // phase 2: waves 0..3 reduce 64 outputs each (1 per thread)
        if (s < 4) {
            float v[16];
#pragma unroll
            for (int s2 = 0; s2 < 16; ++s2) v[s2] = partial[s2][jr];
            const float t0 = (v[0] + v[1]) + (v[2] + v[3]);
            const float t1 = (v[4] + v[5]) + (v[6] + v[7]);
            const float t2 = (v[8] + v[9]) + (v[10] + v[11]);
            const float t3 = (v[12] + v[13]) + (v[14] + v[15]);
            float sum = ((t0 + t1) + (t2 + t3)) + (xp0 + bhj);
            // branchless tanh: clamp, e = exp(2s), (e-1)/(e+1)
            sum = fminf(15.f, fmaxf(-15.f, sum));
            const float e = __expf(2.f * sum);
            const float hn = __fdividef(e - 1.f, e + 1.f);
            hs[jr] = hn;
            obase[(long)t * H_ + jr] = hn;     // fire-and-forget store
            xp0 = xp1;
            xp1 = xp2;
        }
        barrier_lgkm();
    }
}

extern "C" void kernel_launch(void* const* d_in, const int* in_sizes, int n_in,
                              void* d_out, int out_size, void* d_ws, size_t ws_size,
                              hipStream_t stream) {
    const float* x  = (const float*)d_in[0];
    const float* Wx = (const float*)d_in[1];
    const float* bx = (const float*)d_in[2];
    const float* Wh = (const float*)d_in[3];
    const float* bh = (const float*)d_in[4];
    float* out = (float*)d_out;

    xp_kernel<<<(B_ * T_) / 64, 1024, 0, stream>>>(x, Wx, bx, out);
    rnn_kernel<<<B_, 1024, 0, stream>>>(Wh, bh, out);
}